// Round 1
// baseline (227.095 us; speedup 1.0000x reference)
//
#include <hip/hip_runtime.h>

#define T_TOK  16384
#define IN_F   1024
#define OUT_F  1024
#define NE     8
#define BM     128
#define BN     128
#define BK     32
#define NTHREADS 256
#define ROW_TILE_SLOTS 136   // max sum of ceil(len_e/128) = 128 + 8

typedef __bf16 bf16;
typedef bf16  bf16x4 __attribute__((ext_vector_type(4)));
typedef bf16  bf16x8 __attribute__((ext_vector_type(8)));
typedef float f32x4  __attribute__((ext_vector_type(4)));

// Grouped GEMM y[t] = x[t] @ W[e(t)]^T, contiguous ragged segments.
// fp32 in/out, bf16 MFMA compute. 128x128 tile, BK=32.
// v2: register prefetch of next K-tile + LDS double buffer -> global-load
// latency hidden under ds_read+MFMA; ONE barrier per K-step (was two).
__global__ __launch_bounds__(NTHREADS)
void grouped_gemm_f32io_bf16(const float* __restrict__ x,
                             const float* __restrict__ wgt,
                             const int*  __restrict__ seg_lens,
                             float* __restrict__ out)
{
    __shared__ __align__(16) bf16 As[2][BM * BK];   // 2 x 8 KiB
    __shared__ __align__(16) bf16 Bs[2][BN * BK];   // 2 x 8 KiB

    const int m    = blockIdx.y;          // row-tile slot
    const int col0 = blockIdx.x * BN;     // output-feature tile

    // ---- slot m -> (expert, row0, valid rows); segments are contiguous ----
    int e_sel = -1, row0 = 0, rows = 0;
    {
        int start = 0, acct = 0;
        #pragma unroll
        for (int e = 0; e < NE; ++e) {
            int len = seg_lens[e];
            int nt  = (len + BM - 1) >> 7;
            if (e_sel < 0 && m >= acct && m < acct + nt) {
                e_sel = e;
                row0  = start + (m - acct) * BM;
                int rem = start + len - row0;
                rows = rem < BM ? rem : BM;
            }
            acct  += nt;
            start += len;
        }
    }
    if (e_sel < 0) return;   // surplus slot (block-uniform exit, before barriers)

    const int tid  = threadIdx.x;
    const int lane = tid & 63;
    const int wave = tid >> 6;
    const int wm   = (wave >> 1) * 64;   // wave row offset in 128x128 tile
    const int wn   = (wave & 1) * 64;    // wave col offset
    const int quad = lane >> 4;          // 0..3
    const int l16  = lane & 15;

    const float* wbase = wgt + ((size_t)e_sel * OUT_F + (size_t)col0) * IN_F;

    // ---- per-thread loop-invariant source pointers & LDS dest offsets ----
    // chunk c = t*256+tid: row = c>>3, k-quad = c&7 (4 floats each)
    const float* ap[4];
    const float* bp[4];
    int lofs[4];
    #pragma unroll
    for (int t = 0; t < 4; ++t) {
        int c  = t * NTHREADS + tid;
        int rg = row0 + (c >> 3);
        if (rg > T_TOK - 1) rg = T_TOK - 1;     // clamp partial last tile
        ap[t]   = x + (size_t)rg * IN_F + (c & 7) * 4;
        bp[t]   = wbase + (size_t)(c >> 3) * IN_F + (c & 7) * 4;
        lofs[t] = (c >> 3) * BK + (c & 7) * 4;  // element offset in LDS tile
    }

    f32x4 a_st[4], b_st[4];

    // ---- prologue: stage K-tile 0 into buffer 0 ----
    #pragma unroll
    for (int t = 0; t < 4; ++t) {
        a_st[t] = *(const f32x4*)(ap[t]);
        b_st[t] = *(const f32x4*)(bp[t]);
    }
    #pragma unroll
    for (int t = 0; t < 4; ++t) {
        bf16x4 ha, hb;
        #pragma unroll
        for (int j = 0; j < 4; ++j) { ha[j] = (bf16)a_st[t][j]; hb[j] = (bf16)b_st[t][j]; }
        *(bf16x4*)(&As[0][lofs[t]]) = ha;
        *(bf16x4*)(&Bs[0][lofs[t]]) = hb;
    }
    __syncthreads();

    f32x4 acc[4][4] = {};
    int cur = 0;

    for (int k0 = 0; k0 < IN_F; k0 += BK) {
        const int  kn = k0 + BK;
        const bool pf = (kn < IN_F);    // block-uniform

        // ---- issue NEXT tile's global loads first (latency hides under
        //      the ds_read + 16 MFMA below) ----
        if (pf) {
            #pragma unroll
            for (int t = 0; t < 4; ++t) {
                a_st[t] = *(const f32x4*)(ap[t] + kn);
                b_st[t] = *(const f32x4*)(bp[t] + kn);
            }
        }

        // ---- fragments: A[m=l16][k=quad*8+j], B[n=l16][k=quad*8+j] ----
        bf16x8 af[4], bfr[4];
        #pragma unroll
        for (int t = 0; t < 4; ++t)
            af[t] = *(const bf16x8*)(&As[cur][(wm + t * 16 + l16) * BK + quad * 8]);
        #pragma unroll
        for (int u = 0; u < 4; ++u)
            bfr[u] = *(const bf16x8*)(&Bs[cur][(wn + u * 16 + l16) * BK + quad * 8]);

        #pragma unroll
        for (int t = 0; t < 4; ++t)
            #pragma unroll
            for (int u = 0; u < 4; ++u)
                acc[t][u] = __builtin_amdgcn_mfma_f32_16x16x32_bf16(
                    af[t], bfr[u], acc[t][u], 0, 0, 0);

        // ---- convert + store next tile into the ALTERNATE buffer.
        // Safe: buf[cur^1]'s readers (iteration k-1) all passed the barrier
        // that ended iteration k-1 (syncthreads drains their lgkmcnt). ----
        if (pf) {
            #pragma unroll
            for (int t = 0; t < 4; ++t) {
                bf16x4 ha, hb;
                #pragma unroll
                for (int j = 0; j < 4; ++j) { ha[j] = (bf16)a_st[t][j]; hb[j] = (bf16)b_st[t][j]; }
                *(bf16x4*)(&As[cur ^ 1][lofs[t]]) = ha;
                *(bf16x4*)(&Bs[cur ^ 1][lofs[t]]) = hb;
            }
        }
        __syncthreads();   // one barrier per K-step
        cur ^= 1;
    }

    // ---- epilogue: C/D layout col=lane&15, row=quad*4+reg (m89/m91) ----
    #pragma unroll
    for (int t = 0; t < 4; ++t) {
        #pragma unroll
        for (int r = 0; r < 4; ++r) {
            int row = wm + t * 16 + quad * 4 + r;
            if (row < rows) {
                size_t ob = (size_t)(row0 + row) * OUT_F + col0;
                #pragma unroll
                for (int u = 0; u < 4; ++u)
                    out[ob + wn + u * 16 + l16] = acc[t][u][r];
            }
        }
    }
}

extern "C" void kernel_launch(void* const* d_in, const int* in_sizes, int n_in,
                              void* d_out, int out_size, void* d_ws, size_t ws_size,
                              hipStream_t stream) {
    const float* x   = (const float*)d_in[0];
    const float* wgt = (const float*)d_in[1];
    const int*   seg = (const int*)d_in[2];
    float* out = (float*)d_out;

    dim3 grid(OUT_F / BN, ROW_TILE_SLOTS, 1);
    dim3 block(NTHREADS, 1, 1);
    grouped_gemm_f32io_bf16<<<grid, block, 0, stream>>>(x, wgt, seg, out);
}

// Round 2
// 218.673 us; speedup vs baseline: 1.0385x; 1.0385x over previous
//
#include <hip/hip_runtime.h>

#define T_TOK  16384
#define IN_F   1024
#define OUT_F  1024
#define NE     8
#define BM     128
#define BN     128
#define BK     32
#define NTHREADS 256
#define ROW_TILE_SLOTS 136   // max sum of ceil(len_e/128) = 128 + 8

typedef __bf16 bf16;
typedef bf16  bf16x4 __attribute__((ext_vector_type(4)));
typedef bf16  bf16x8 __attribute__((ext_vector_type(8)));
typedef float f32x4  __attribute__((ext_vector_type(4)));

// ---------------------------------------------------------------------------
// Pass 1: fp32 -> bf16 convert of x and W into workspace (one launch).
// Memory-bound; vectorized f32x4 read, bf16x4 (8B) write.
// ---------------------------------------------------------------------------
#define NX_CHUNKS (T_TOK * IN_F / 4)                 // 4.19M f32x4 chunks
#define NW_CHUNKS (NE * OUT_F * IN_F / 4)            // 2.10M
#define NTOT_CHUNKS (NX_CHUNKS + NW_CHUNKS)

__global__ __launch_bounds__(NTHREADS)
void cvt_f32_to_bf16(const float* __restrict__ x, const float* __restrict__ w,
                     bf16* __restrict__ xb, bf16* __restrict__ wb)
{
    for (int i = blockIdx.x * NTHREADS + threadIdx.x; i < NTOT_CHUNKS;
         i += gridDim.x * NTHREADS) {
        const bool isx = (i < NX_CHUNKS);
        const int  j   = isx ? i : i - NX_CHUNKS;
        f32x4 v = isx ? ((const f32x4*)x)[j] : ((const f32x4*)w)[j];
        bf16x4 h;
        #pragma unroll
        for (int k = 0; k < 4; ++k) h[k] = (bf16)v[k];
        if (isx) ((bf16x4*)xb)[j] = h;
        else     ((bf16x4*)wb)[j] = h;
    }
}

// ---------------------------------------------------------------------------
// Pass 2: grouped GEMM on bf16 operands, m97 structure:
// global_load_lds width-16 staging, single-buffer LDS, 2 barriers/K-step.
// ---------------------------------------------------------------------------
__device__ __forceinline__ void gld_lds16(const bf16* g, bf16* l) {
    __builtin_amdgcn_global_load_lds(
        (const __attribute__((address_space(1))) void*)g,
        (__attribute__((address_space(3))) void*)l,
        16, 0, 0);
}

__global__ __launch_bounds__(NTHREADS)
void grouped_gemm_bf16(const bf16* __restrict__ xb,
                       const bf16* __restrict__ wb,
                       const int*  __restrict__ seg_lens,
                       float* __restrict__ out)
{
    __shared__ __align__(16) bf16 As[BM * BK];   // 8 KiB, row-major [128][32]
    __shared__ __align__(16) bf16 Bs[BN * BK];   // 8 KiB

    const int m    = blockIdx.y;
    const int col0 = blockIdx.x * BN;

    // ---- slot m -> (expert, row0, valid rows) ----
    int e_sel = -1, row0 = 0, rows = 0;
    {
        int start = 0, acct = 0;
        #pragma unroll
        for (int e = 0; e < NE; ++e) {
            int len = seg_lens[e];
            int nt  = (len + BM - 1) >> 7;
            if (e_sel < 0 && m >= acct && m < acct + nt) {
                e_sel = e;
                row0  = start + (m - acct) * BM;
                int rem = start + len - row0;
                rows = rem < BM ? rem : BM;
            }
            acct  += nt;
            start += len;
        }
    }
    if (e_sel < 0) return;   // surplus slot, uniform exit before any barrier

    const int tid  = threadIdx.x;
    const int lane = tid & 63;
    const int wave = tid >> 6;
    const int wm   = (wave >> 1) * 64;
    const int wn   = (wave & 1) * 64;
    const int quad = lane >> 4;
    const int l16  = lane & 15;

    const bf16* wbase = wb + ((size_t)e_sel * OUT_F + (size_t)col0) * IN_F;

    // ---- staging geometry (global_load_lds, wave-uniform LDS base) ----
    // Tile = 128 rows x 32 bf16 (64 B/row) = 8 KiB. One (wave,pass) issue
    // covers 1024 B = 16 rows; 4 waves x 2 passes cover the tile.
    // lane l -> row (l>>2) within group, k-offset (l&3)*8 elements.
    const int grp0 = wave * 16 + (lane >> 2);          // pass 0 row
    const int kofs = (lane & 3) * 8;                   // bf16 elements
    // per-lane global row indices (A rows clamped into x bounds)
    int rgA0 = row0 + grp0;          if (rgA0 > T_TOK - 1) rgA0 = T_TOK - 1;
    int rgA1 = row0 + grp0 + 64;     if (rgA1 > T_TOK - 1) rgA1 = T_TOK - 1;
    const bf16* gA0 = xb + (size_t)rgA0 * IN_F + kofs;
    const bf16* gA1 = xb + (size_t)rgA1 * IN_F + kofs;
    const bf16* gB0 = wbase + (size_t)grp0 * IN_F + kofs;
    const bf16* gB1 = wbase + (size_t)(grp0 + 64) * IN_F + kofs;
    // wave-uniform LDS destinations (HW scatters lane*16 internally)
    bf16* lA0 = As + wave * 512;              // bytes: wave*1024
    bf16* lA1 = As + (4 + wave) * 512;
    bf16* lB0 = Bs + wave * 512;
    bf16* lB1 = Bs + (4 + wave) * 512;

    f32x4 acc[4][4] = {};

    for (int k0 = 0; k0 < IN_F; k0 += BK) {
        // ---- stage tile k0 (async DMA global->LDS, no VGPR round-trip) ----
        gld_lds16(gA0 + k0, lA0);
        gld_lds16(gA1 + k0, lA1);
        gld_lds16(gB0 + k0, lB0);
        gld_lds16(gB1 + k0, lB1);
        __syncthreads();   // drains vmcnt -> LDS tile visible

        // ---- fragments: A[m=l16][k=quad*8+j], B[n=l16][k=quad*8+j] ----
        bf16x8 af[4], bfr[4];
        #pragma unroll
        for (int t = 0; t < 4; ++t)
            af[t] = *(const bf16x8*)(&As[(wm + t * 16 + l16) * BK + quad * 8]);
        #pragma unroll
        for (int u = 0; u < 4; ++u)
            bfr[u] = *(const bf16x8*)(&Bs[(wn + u * 16 + l16) * BK + quad * 8]);

        #pragma unroll
        for (int t = 0; t < 4; ++t)
            #pragma unroll
            for (int u = 0; u < 4; ++u)
                acc[t][u] = __builtin_amdgcn_mfma_f32_16x16x32_bf16(
                    af[t], bfr[u], acc[t][u], 0, 0, 0);

        __syncthreads();   // all reads done before next restage
    }

    // ---- epilogue: C/D layout col=lane&15, row=quad*4+reg (m89/m91) ----
    #pragma unroll
    for (int t = 0; t < 4; ++t) {
        #pragma unroll
        for (int r = 0; r < 4; ++r) {
            int row = wm + t * 16 + quad * 4 + r;
            if (row < rows) {
                size_t ob = (size_t)(row0 + row) * OUT_F + col0;
                #pragma unroll
                for (int u = 0; u < 4; ++u)
                    out[ob + wn + u * 16 + l16] = acc[t][u][r];
            }
        }
    }
}

// ---------------------------------------------------------------------------
// Fallback (ws too small): round-0 kernel — fp32 loads, in-loop cvt.
// Known-good at 121.9 us/dispatch.
// ---------------------------------------------------------------------------
__global__ __launch_bounds__(NTHREADS)
void grouped_gemm_f32io_bf16(const float* __restrict__ x,
                             const float* __restrict__ wgt,
                             const int*  __restrict__ seg_lens,
                             float* __restrict__ out)
{
    __shared__ __align__(16) bf16 As[BM * BK];
    __shared__ __align__(16) bf16 Bs[BN * BK];

    const int m    = blockIdx.y;
    const int col0 = blockIdx.x * BN;

    int e_sel = -1, row0 = 0, rows = 0;
    {
        int start = 0, acct = 0;
        #pragma unroll
        for (int e = 0; e < NE; ++e) {
            int len = seg_lens[e];
            int nt  = (len + BM - 1) >> 7;
            if (e_sel < 0 && m >= acct && m < acct + nt) {
                e_sel = e;
                row0  = start + (m - acct) * BM;
                int rem = start + len - row0;
                rows = rem < BM ? rem : BM;
            }
            acct  += nt;
            start += len;
        }
    }
    if (e_sel < 0) return;

    const int tid  = threadIdx.x;
    const int lane = tid & 63;
    const int wave = tid >> 6;
    const int wm   = (wave >> 1) * 64;
    const int wn   = (wave & 1) * 64;
    const int quad = lane >> 4;
    const int l16  = lane & 15;

    const float* wbase = wgt + ((size_t)e_sel * OUT_F + (size_t)col0) * IN_F;

    f32x4 acc[4][4] = {};

    for (int k0 = 0; k0 < IN_F; k0 += BK) {
        f32x4 a_st[4], b_st[4];
        #pragma unroll
        for (int t = 0; t < 4; ++t) {
            int c  = t * NTHREADS + tid;
            int rg = row0 + (c >> 3);
            if (rg > T_TOK - 1) rg = T_TOK - 1;
            a_st[t] = *(const f32x4*)(x + (size_t)rg * IN_F + k0 + (c & 7) * 4);
            b_st[t] = *(const f32x4*)(wbase + (size_t)(c >> 3) * IN_F + k0 + (c & 7) * 4);
        }

        __syncthreads();

        #pragma unroll
        for (int t = 0; t < 4; ++t) {
            int c = t * NTHREADS + tid;
            bf16x4 ha, hb;
            #pragma unroll
            for (int j = 0; j < 4; ++j) { ha[j] = (bf16)a_st[t][j]; hb[j] = (bf16)b_st[t][j]; }
            *(bf16x4*)(&As[(c >> 3) * BK + (c & 7) * 4]) = ha;
            *(bf16x4*)(&Bs[(c >> 3) * BK + (c & 7) * 4]) = hb;
        }
        __syncthreads();

        bf16x8 af[4], bfr[4];
        #pragma unroll
        for (int t = 0; t < 4; ++t)
            af[t] = *(const bf16x8*)(&As[(wm + t * 16 + l16) * BK + quad * 8]);
        #pragma unroll
        for (int u = 0; u < 4; ++u)
            bfr[u] = *(const bf16x8*)(&Bs[(wn + u * 16 + l16) * BK + quad * 8]);

        #pragma unroll
        for (int t = 0; t < 4; ++t)
            #pragma unroll
            for (int u = 0; u < 4; ++u)
                acc[t][u] = __builtin_amdgcn_mfma_f32_16x16x32_bf16(
                    af[t], bfr[u], acc[t][u], 0, 0, 0);
    }

    #pragma unroll
    for (int t = 0; t < 4; ++t) {
        #pragma unroll
        for (int r = 0; r < 4; ++r) {
            int row = wm + t * 16 + quad * 4 + r;
            if (row < rows) {
                size_t ob = (size_t)(row0 + row) * OUT_F + col0;
                #pragma unroll
                for (int u = 0; u < 4; ++u)
                    out[ob + wn + u * 16 + l16] = acc[t][u][r];
            }
        }
    }
}

extern "C" void kernel_launch(void* const* d_in, const int* in_sizes, int n_in,
                              void* d_out, int out_size, void* d_ws, size_t ws_size,
                              hipStream_t stream) {
    const float* x   = (const float*)d_in[0];
    const float* wgt = (const float*)d_in[1];
    const int*   seg = (const int*)d_in[2];
    float* out = (float*)d_out;

    const size_t xbytes = (size_t)T_TOK * IN_F * sizeof(bf16);       // 33.55 MB
    const size_t wbytes = (size_t)NE * OUT_F * IN_F * sizeof(bf16);  // 16.78 MB

    dim3 grid(OUT_F / BN, ROW_TILE_SLOTS, 1);
    dim3 block(NTHREADS, 1, 1);

    if (ws_size >= xbytes + wbytes) {
        bf16* xb = (bf16*)d_ws;
        bf16* wb = (bf16*)((char*)d_ws + xbytes);
        cvt_f32_to_bf16<<<dim3(2048, 1, 1), block, 0, stream>>>(x, wgt, xb, wb);
        grouped_gemm_bf16<<<grid, block, 0, stream>>>(xb, wb, seg, out);
    } else {
        grouped_gemm_f32io_bf16<<<grid, block, 0, stream>>>(x, wgt, seg, out);
    }
}